// Round 3
// baseline (292.181 us; speedup 1.0000x reference)
//
#include <hip/hip_runtime.h>
#include <hip/hip_fp16.h>
#include <stdint.h>
#include <stddef.h>

// ============================================================================
// HTensorSquare: out[b] = sum_paths alpha * einsum(uvw,ijk,bui,bvj->bwk)
// Irreps in/out: 64x0e + 32x1o + 16x2e (DIM 240), B = 20000.
// 3 fused GEMMs (one per output irrep). A-operand (CG-transformed products)
// generated in registers with packed fp16 math; B = preprocessed fp16 weights.
// Round 3: same as Round 2 design, fixing cvt_pkrtz return-type bit_cast.
// ============================================================================

// ---------------------------------------------------------------------------
// Compile-time Clebsch-Gordan machinery (exact port of the reference numpy).
// ---------------------------------------------------------------------------
namespace cg {

struct Cx { double re, im; };
constexpr Cx cmul(Cx a, Cx b){ return { a.re*b.re - a.im*b.im, a.re*b.im + a.im*b.re }; }

constexpr double fact(int n){ double r = 1.0; for (int i = 2; i <= n; ++i) r *= (double)i; return r; }

constexpr double csqrt(double x){
  if (x <= 0.0) return 0.0;
  double r = x > 1.0 ? x : 1.0;
  for (int i = 0; i < 50; ++i) r = 0.5*(r + x/r);
  return r;
}

constexpr double neg1pow(int k){ return (k % 2 == 0) ? 1.0 : -1.0; }

constexpr double su2_cg(int j1,int m1,int j2,int m2,int j3,int m3){
  if (m3 != m1 + m2) return 0.0;
  int vmin = -j1 + j2 + m3;
  if (-j1 + m1 > vmin) vmin = -j1 + m1;
  if (0 > vmin) vmin = 0;
  int vmax = j2 + j3 + m1;
  if (j3 - j1 + j2 < vmax) vmax = j3 - j1 + j2;
  if (j3 + m3 < vmax) vmax = j3 + m3;
  if (vmax < vmin) return 0.0;
  double C = csqrt((2.0*j3 + 1.0)*fact(j3+j1-j2)*fact(j3-j1+j2)*fact(j1+j2-j3)
                   *fact(j3+m3)*fact(j3-m3)
                   /(fact(j1+j2+j3+1)*fact(j1-m1)*fact(j1+m1)*fact(j2-m2)*fact(j2+m2)));
  double S = 0.0;
  for (int v = vmin; v <= vmax; ++v)
    S += neg1pow(v + j2 + m2)*fact(j2+j3+m1-v)*fact(j1-m1+v)
       /(fact(v)*fact(j3-j1+j2-v)*fact(j3+m3-v)*fact(v+j1-j2-m3));
  return C*S;
}

struct QM { Cx v[5][5]; };
constexpr QM qmat(int l){
  QM q{};
  const double r2 = 0.70710678118654752440;
  for (int m = -l; m < 0; ++m){
    q.v[l+m][l-m] = Cx{ r2, 0.0 };
    q.v[l+m][l+m] = Cx{ 0.0, -r2 };
  }
  q.v[l][l] = Cx{ 1.0, 0.0 };
  for (int m = 1; m <= l; ++m){
    double s = neg1pow(m)*r2;
    q.v[l+m][l+m] = Cx{ s, 0.0 };
    q.v[l+m][l-m] = Cx{ 0.0, s };
  }
  Cx ph = (l % 4 == 0) ? Cx{1,0} : (l % 4 == 1) ? Cx{0,-1} : (l % 4 == 2) ? Cx{-1,0} : Cx{0,1};
  QM out{};
  for (int i = 0; i < 5; ++i) for (int j = 0; j < 5; ++j) out.v[i][j] = cmul(ph, q.v[i][j]);
  return out;
}

struct CGT { double v[5][5][5]; };
constexpr CGT cg_tab(int l1,int l2,int l3){
  double C[5][5][5] = {};
  for (int m1 = -l1; m1 <= l1; ++m1)
    for (int m2 = -l2; m2 <= l2; ++m2)
      for (int m3 = -l3; m3 <= l3; ++m3)
        C[l1+m1][l2+m2][l3+m3] = su2_cg(l1,m1,l2,m2,l3,m3);
  QM Q1 = qmat(l1), Q2 = qmat(l2), Q3 = qmat(l3);
  const int n1 = 2*l1+1, n2 = 2*l2+1, n3 = 2*l3+1;
  const double norm = csqrt(2.0*l3 + 1.0);
  CGT R{};
  for (int j = 0; j < n1; ++j)
    for (int l = 0; l < n2; ++l)
      for (int m = 0; m < n3; ++m){
        Cx s{0,0};
        for (int i = 0; i < n1; ++i)
          for (int k = 0; k < n2; ++k)
            for (int n = 0; n < n3; ++n){
              double c = C[i][k][n];
              if (c != 0.0){
                Cx q3c{ Q3.v[n][m].re, -Q3.v[n][m].im };
                Cx t = cmul(cmul(Q1.v[i][j], Q2.v[k][l]), q3c);
                s.re += t.re*c; s.im += t.im*c;
              }
            }
        R.v[j][l][m] = s.re * norm;
      }
  return R;
}

constexpr double tab_sumsq(const CGT& t, int n1, int n2, int n3){
  double s = 0;
  for (int i = 0; i < n1; ++i) for (int j = 0; j < n2; ++j) for (int k = 0; k < n3; ++k)
    s += t.v[i][j][k]*t.v[i][j][k];
  return s;
}

} // namespace cg

constexpr cg::CGT T121 = cg::cg_tab(1,2,1);
constexpr cg::CGT T211 = cg::cg_tab(2,1,1);
constexpr cg::CGT T112 = cg::cg_tab(1,1,2);
constexpr cg::CGT T222 = cg::cg_tab(2,2,2);
constexpr double C000 = cg::cg_tab(0,0,0).v[0][0][0];
constexpr double C011 = cg::cg_tab(0,1,1).v[0][0][0];
constexpr double C022 = cg::cg_tab(0,2,2).v[0][0][0];
constexpr double C101 = cg::cg_tab(1,0,1).v[0][0][0];
constexpr double C110 = cg::cg_tab(1,1,0).v[0][0][0];
constexpr double C220 = cg::cg_tab(2,2,0).v[0][0][0];
constexpr double C202 = cg::cg_tab(2,0,2).v[0][0][0];

static_assert(C000 > 0.99 && C000 < 1.01, "C000");
static_assert(C011 > 1.72 && C011 < 1.74, "C011");
static_assert(C101 > 1.72 && C101 < 1.74, "C101");
static_assert(C022 > 2.22 && C022 < 2.25, "C022");
static_assert(C202 > 2.22 && C202 < 2.25, "C202");
static_assert(C110*C110 > 0.332 && C110*C110 < 0.334, "C110");
static_assert(C220*C220 > 0.199 && C220*C220 < 0.201, "C220");
static_assert(cg::tab_sumsq(T121,3,5,3) > 8.9  && cg::tab_sumsq(T121,3,5,3) < 9.1,  "T121");
static_assert(cg::tab_sumsq(T211,5,3,3) > 8.9  && cg::tab_sumsq(T211,5,3,3) < 9.1,  "T211");
static_assert(cg::tab_sumsq(T112,3,3,5) > 24.9 && cg::tab_sumsq(T112,3,3,5) < 25.1, "T112");
static_assert(cg::tab_sumsq(T222,5,5,5) > 24.9 && cg::tab_sumsq(T222,5,5,5) < 25.1, "T222");

constexpr double A0 = 1.0/cg::csqrt(5376.0);
constexpr double A1 = 1.0/cg::csqrt(5120.0);
constexpr double A2 = 1.0/cg::csqrt(3328.0);

constexpr double S000 = A0*C000, S110 = A0*C110, S220 = A0*C220;
constexpr double S011 = A1*C011, S101 = A1*C101, S121 = A1, S211 = A1;
constexpr double S022 = A2*C022, S112 = A2,      S202 = A2*C202, S222 = A2;

// Workspace layout (fp16 elements): WT0[64][K0], WT1[32][K1], WT2[16][K2]
constexpr int K0 = 5376, K1 = 5120, K2 = 3328;
constexpr int WT1_OFF = 64*K0;              // 344064
constexpr int WT2_OFF = WT1_OFF + 32*K1;    // 507904
constexpr int WT_TOT  = WT2_OFF + 16*K2;    // 561152

// ---------------------------------------------------------------------------
// Device helpers
// ---------------------------------------------------------------------------
typedef _Float16 half8v __attribute__((ext_vector_type(8)));
typedef _Float16 half4v __attribute__((ext_vector_type(4)));
typedef _Float16 half2v __attribute__((ext_vector_type(2)));
typedef float    float4v __attribute__((ext_vector_type(4)));

union Frag { half8v h8; half2v h2[4]; };

__device__ __forceinline__ half2v pfma(half2v a, half2v b, half2v c){
  __half2 r = __hfma2(__builtin_bit_cast(__half2, a),
                      __builtin_bit_cast(__half2, b),
                      __builtin_bit_cast(__half2, c));
  return __builtin_bit_cast(half2v, r);
}
__device__ __forceinline__ half2v pmul(half2v a, half2v b){
  __half2 r = __hmul2(__builtin_bit_cast(__half2, a), __builtin_bit_cast(__half2, b));
  return __builtin_bit_cast(half2v, r);
}
__device__ __forceinline__ half2v bc2(const _Float16* p){
  _Float16 h = *p; half2v r = { h, h }; return r;
}
__device__ __forceinline__ half2v pk2(float a, float b){
  // v_cvt_pkrtz_f16_f32 returns __fp16x2; bit-identical to half2v
  return __builtin_bit_cast(half2v, __builtin_amdgcn_cvt_pkrtz(a, b));
}
__device__ __forceinline__ half8v ldH(const _Float16* p){
  return *reinterpret_cast<const half8v*>(p);
}
__device__ __forceinline__ float4v MF(half8v a, half8v b, float4v c){
  return __builtin_amdgcn_mfma_f32_16x16x32_f16(a, b, c, 0, 0, 0);
}

#define NZ(c) ((c) > 1e-12 || (c) < -1e-12)

constexpr int XS = 248;   // x-tile LDS row stride in halfs (496 B: 16B-aligned rows)

// ---------------------------------------------------------------------------
// Weight preprocessing: transposed fp16 weight matrices, scales + K-perms
// folded in.  1D grid over WT_TOT elements.  wt index == output index.
// ---------------------------------------------------------------------------
__global__ void tsq_prep(const float* __restrict__ w0, const float* __restrict__ w1,
                         const float* __restrict__ w2, const float* __restrict__ w3,
                         const float* __restrict__ w4, const float* __restrict__ w5,
                         const float* __restrict__ w6, const float* __restrict__ w7,
                         const float* __restrict__ w8, const float* __restrict__ w9,
                         const float* __restrict__ w10, _Float16* __restrict__ wt){
  const int idx = blockIdx.x*256 + threadIdx.x;
  if (idx >= WT_TOT) return;
  float v;
  if (idx < WT1_OFF){
    const int n = idx / K0, k = idx - n*K0;
    if (k < 4096)       v = w0[k*64 + n] * (float)S000;                 // (0,0,0) k=u*64+v
    else if (k < 5120)  v = w4[(k-4096)*64 + n] * (float)S110;          // (1,1,0) k=u*32+v
    else                v = w9[(k-5120)*64 + n] * (float)S220;          // (2,2,0) k=u*16+v
  } else if (idx < WT2_OFF){
    const int j = idx - WT1_OFF;
    const int n = j / K1, k = j - n*K1;
    if (k < 2048){                                  // (0,1,1) reordered k=v*64+u
      const int u = k & 63, vv = k >> 6;
      v = w1[(u*32 + vv)*32 + n] * (float)S011;
    } else if (k < 4096){                           // (1,0,1) natural k=u*64+v
      v = w3[(k-2048)*32 + n] * (float)S101;
    } else if (k < 4608){                           // (1,2,1) reordered k=v*32+u
      const int kl = k - 4096; const int u = kl & 31, vv = kl >> 5;
      v = w6[(u*16 + vv)*32 + n] * (float)S121;
    } else {                                        // (2,1,1) natural k=u*32+v
      v = w8[(k-4608)*32 + n] * (float)S211;
    }
  } else {
    const int j = idx - WT2_OFF;
    const int n = j / K2, k = j - n*K2;
    if (k < 1024){                                  // (0,2,2) reordered k=v*64+u
      const int u = k & 63, vv = k >> 6;
      v = w2[(u*16 + vv)*16 + n] * (float)S022;
    } else if (k < 2048){                           // (1,1,2) natural k=u*32+v
      v = w5[(k-1024)*16 + n] * (float)S112;
    } else if (k < 3072){                           // (2,0,2) natural k=u*64+v
      v = w7[(k-2048)*16 + n] * (float)S202;
    } else {                                        // (2,2,2) natural k=u*16+v
      v = w10[(k-3072)*16 + n] * (float)S222;
    }
  }
  wt[idx] = (_Float16)v;
}

// ---------------------------------------------------------------------------
// Main kernel.  grid (3, 313), block 256 (4 waves).  blockIdx.x = GEMM id,
// blockIdx.y = batch tile of 64 rows.  Each wave owns 16 rows, full K.
// ---------------------------------------------------------------------------
__global__ __launch_bounds__(256, 4)
void tsq_main(const float* __restrict__ x, const _Float16* __restrict__ wt,
              float* __restrict__ out){
  __shared__ _Float16 lh[64*XS];   // 31744 B
  const int g    = blockIdx.x;
  const int b0   = blockIdx.y * 64;
  const int tid  = threadIdx.x;
  const int wv   = tid >> 6;
  const int lane = tid & 63;
  const int col  = lane & 15;
  const int tg   = lane >> 4;

  // ---- stage x tile: fp32 global -> fp16 LDS ----
  for (int i = tid; i < 64*60; i += 256){
    const int r = i / 60, c = i - r*60;
    int gb = b0 + r; if (gb > 19999) gb = 19999;
    const float4 v = *(reinterpret_cast<const float4*>(x + (size_t)gb*240) + c);
    half2v p0 = pk2(v.x, v.y);
    half2v p1 = pk2(v.z, v.w);
    half4v h; h[0]=p0[0]; h[1]=p0[1]; h[2]=p1[0]; h[3]=p1[1];
    *reinterpret_cast<half4v*>(&lh[r*XS + c*4]) = h;
  }
  __syncthreads();

  const float4v z4 = {0.f, 0.f, 0.f, 0.f};
  const _Float16* rh = &lh[(wv*16 + col)*XS];   // this lane's x row

  // x0 windows (both 32-halves), 8 halfs each: x0 at halfs [0,64)
  Frag x0w[2];
  x0w[0].h8 = ldH(rh + tg*8);
  x0w[1].h8 = ldH(rh + 32 + tg*8);

  if (g == 0){
    // ============ GEMM 0: out[:,0:64], K=5376, N=64 (4 n-tiles) ============
    const _Float16* bp[4];
    #pragma unroll
    for (int nt = 0; nt < 4; ++nt) bp[nt] = wt + (size_t)(nt*16 + col)*K0 + tg*8;
    float4v acc[4];
    #pragma unroll
    for (int nt = 0; nt < 4; ++nt) acc[nt] = z4;

    // --- (0,0,0): k=u*64+v, 64 double-steps ---
    #pragma unroll 2
    for (int so = 0; so < 64; ++so){
      half8v bf[2][4];
      #pragma unroll
      for (int sel = 0; sel < 2; ++sel)
        #pragma unroll
        for (int nt = 0; nt < 4; ++nt) bf[sel][nt] = ldH(bp[nt] + (2*so + sel)*32);
      const half2v xu2 = bc2(rh + so);
      #pragma unroll
      for (int sel = 0; sel < 2; ++sel){
        Frag af;
        #pragma unroll
        for (int tp = 0; tp < 4; ++tp) af.h2[tp] = pmul(xu2, x0w[sel].h2[tp]);
        #pragma unroll
        for (int nt = 0; nt < 4; ++nt) acc[nt] = MF(af.h8, bf[sel][nt], acc[nt]);
      }
    }
    // --- (1,1,0): k=u*32+v, 32 steps ; pair-transposed x1 window ---
    half2v xP[3][4];
    #pragma unroll
    for (int i = 0; i < 3; ++i)
      #pragma unroll
      for (int tp = 0; tp < 4; ++tp){
        _Float16 e0 = rh[64 + (tg*8 + 2*tp    )*3 + i];
        _Float16 e1 = rh[64 + (tg*8 + 2*tp + 1)*3 + i];
        half2v p = { e0, e1 }; xP[i][tp] = p;
      }
    #pragma unroll 2
    for (int u = 0; u < 32; ++u){
      half8v bf[4];
      #pragma unroll
      for (int nt = 0; nt < 4; ++nt) bf[nt] = ldH(bp[nt] + (128 + u)*32);
      const half2v u0 = bc2(rh + 64 + u*3), u1 = bc2(rh + 64 + u*3 + 1), u2 = bc2(rh + 64 + u*3 + 2);
      Frag af;
      #pragma unroll
      for (int tp = 0; tp < 4; ++tp)
        af.h2[tp] = pfma(xP[2][tp], u2, pfma(xP[1][tp], u1, pmul(xP[0][tp], u0)));
      #pragma unroll
      for (int nt = 0; nt < 4; ++nt) acc[nt] = MF(af.h8, bf[nt], acc[nt]);
    }
    // --- (2,2,0): k=u*16+v, 8 steps ; pair-transposed x2 half-window ---
    half2v xQ[5][4];
    #pragma unroll
    for (int i = 0; i < 5; ++i)
      #pragma unroll
      for (int tp = 0; tp < 4; ++tp){
        _Float16 e0 = rh[160 + ((tg&1)*8 + 2*tp    )*5 + i];
        _Float16 e1 = rh[160 + ((tg&1)*8 + 2*tp + 1)*5 + i];
        half2v p = { e0, e1 }; xQ[i][tp] = p;
      }
    #pragma unroll 2
    for (int s8 = 0; s8 < 8; ++s8){
      half8v bf[4];
      #pragma unroll
      for (int nt = 0; nt < 4; ++nt) bf[nt] = ldH(bp[nt] + (160 + s8)*32);
      const int u = 2*s8 + (tg >> 1);
      half2v xu[5];
      #pragma unroll
      for (int i = 0; i < 5; ++i) xu[i] = bc2(rh + 160 + u*5 + i);
      Frag af;
      #pragma unroll
      for (int tp = 0; tp < 4; ++tp){
        half2v a = pmul(xQ[0][tp], xu[0]);
        #pragma unroll
        for (int i = 1; i < 5; ++i) a = pfma(xQ[i][tp], xu[i], a);
        af.h2[tp] = a;
      }
      #pragma unroll
      for (int nt = 0; nt < 4; ++nt) acc[nt] = MF(af.h8, bf[nt], acc[nt]);
    }
    // --- store ---
    #pragma unroll
    for (int r = 0; r < 4; ++r){
      const int b = b0 + wv*16 + tg*4 + r;
      if (b < 20000){
        #pragma unroll
        for (int nt = 0; nt < 4; ++nt) out[(size_t)b*240 + nt*16 + col] = acc[nt][r];
      }
    }

  } else if (g == 1){
    // ========== GEMM 1: out[:,64:160] (w*3+kk), K=5120, N=32 ==========
    const _Float16* W = wt + WT1_OFF;
    const _Float16* bp[2];
    #pragma unroll
    for (int nt = 0; nt < 2; ++nt) bp[nt] = W + (size_t)(nt*16 + col)*K1 + tg*8;
    float4v acc[3][2];
    #pragma unroll
    for (int kk = 0; kk < 3; ++kk)
      #pragma unroll
      for (int nt = 0; nt < 2; ++nt) acc[kk][nt] = z4;

    // --- (0,1,1)+(1,0,1): slow idx m over x1, fast = x0 window; 64 double-steps ---
    #pragma unroll 2
    for (int so = 0; so < 64; ++so){
      half8v bf[2][2];
      #pragma unroll
      for (int sel = 0; sel < 2; ++sel)
        #pragma unroll
        for (int nt = 0; nt < 2; ++nt) bf[sel][nt] = ldH(bp[nt] + (2*so + sel)*32);
      const int m = so & 31;
      const half2v c0 = bc2(rh + 64 + m*3), c1 = bc2(rh + 64 + m*3 + 1), c2 = bc2(rh + 64 + m*3 + 2);
      #pragma unroll
      for (int sel = 0; sel < 2; ++sel){
        Frag a0, a1, a2;
        #pragma unroll
        for (int tp = 0; tp < 4; ++tp){
          a0.h2[tp] = pmul(c0, x0w[sel].h2[tp]);
          a1.h2[tp] = pmul(c1, x0w[sel].h2[tp]);
          a2.h2[tp] = pmul(c2, x0w[sel].h2[tp]);
        }
        #pragma unroll
        for (int nt = 0; nt < 2; ++nt){
          acc[0][nt] = MF(a0.h8, bf[sel][nt], acc[0][nt]);
          acc[1][nt] = MF(a1.h8, bf[sel][nt], acc[1][nt]);
          acc[2][nt] = MF(a2.h8, bf[sel][nt], acc[2][nt]);
        }
      }
    }
    // pair-transposed x1 window over u = tg*8..+8 (used by both CG phases)
    half2v xP[3][4];
    #pragma unroll
    for (int i = 0; i < 3; ++i)
      #pragma unroll
      for (int tp = 0; tp < 4; ++tp){
        _Float16 e0 = rh[64 + (tg*8 + 2*tp    )*3 + i];
        _Float16 e1 = rh[64 + (tg*8 + 2*tp + 1)*3 + i];
        half2v p = { e0, e1 }; xP[i][tp] = p;
      }
    // --- (1,2,1): k=v*32+u, 16 steps; y[i][kk] = sum_j C[i,j,kk]*x2[v][j] ---
    #pragma unroll 2
    for (int v = 0; v < 16; ++v){
      half8v bf[2];
      #pragma unroll
      for (int nt = 0; nt < 2; ++nt) bf[nt] = ldH(bp[nt] + (128 + v)*32);
      float xj[5];
      #pragma unroll
      for (int j = 0; j < 5; ++j) xj[j] = (float)rh[160 + v*5 + j];
      half2v y2[3][3];
      #pragma unroll
      for (int i = 0; i < 3; ++i)
        #pragma unroll
        for (int kk = 0; kk < 3; ++kk){
          float y = 0.f;
          #pragma unroll
          for (int j = 0; j < 5; ++j){
            const double cd = T121.v[i][j][kk];
            if (NZ(cd)) y = fmaf((float)cd, xj[j], y);
          }
          y2[i][kk] = pk2(y, y);
        }
      #pragma unroll
      for (int kk = 0; kk < 3; ++kk){
        Frag af;
        #pragma unroll
        for (int tp = 0; tp < 4; ++tp)
          af.h2[tp] = pfma(xP[2][tp], y2[2][kk], pfma(xP[1][tp], y2[1][kk], pmul(xP[0][tp], y2[0][kk])));
        #pragma unroll
        for (int nt = 0; nt < 2; ++nt) acc[kk][nt] = MF(af.h8, bf[nt], acc[kk][nt]);
      }
    }
    // --- (2,1,1): k=u*32+v, 16 steps; z[j][kk] = sum_i C[i,j,kk]*x2[u][i] ---
    #pragma unroll 2
    for (int u = 0; u < 16; ++u){
      half8v bf[2];
      #pragma unroll
      for (int nt = 0; nt < 2; ++nt) bf[nt] = ldH(bp[nt] + (144 + u)*32);
      float xi[5];
      #pragma unroll
      for (int i = 0; i < 5; ++i) xi[i] = (float)rh[160 + u*5 + i];
      half2v z2[3][3];
      #pragma unroll
      for (int j = 0; j < 3; ++j)
        #pragma unroll
        for (int kk = 0; kk < 3; ++kk){
          float z = 0.f;
          #pragma unroll
          for (int i = 0; i < 5; ++i){
            const double cd = T211.v[i][j][kk];
            if (NZ(cd)) z = fmaf((float)cd, xi[i], z);
          }
          z2[j][kk] = pk2(z, z);
        }
      #pragma unroll
      for (int kk = 0; kk < 3; ++kk){
        Frag af;
        #pragma unroll
        for (int tp = 0; tp < 4; ++tp)
          af.h2[tp] = pfma(xP[2][tp], z2[2][kk], pfma(xP[1][tp], z2[1][kk], pmul(xP[0][tp], z2[0][kk])));
        #pragma unroll
        for (int nt = 0; nt < 2; ++nt) acc[kk][nt] = MF(af.h8, bf[nt], acc[kk][nt]);
      }
    }
    // --- store (3 consecutive floats per (b,w)) ---
    #pragma unroll
    for (int r = 0; r < 4; ++r){
      const int b = b0 + wv*16 + tg*4 + r;
      if (b < 20000){
        #pragma unroll
        for (int nt = 0; nt < 2; ++nt){
          const int w = nt*16 + col;
          float* o = out + (size_t)b*240 + 64 + 3*w;
          o[0] = acc[0][nt][r]; o[1] = acc[1][nt][r]; o[2] = acc[2][nt][r];
        }
      }
    }

  } else {
    // ========== GEMM 2: out[:,160:240] (w*5+kk), K=3328, N=16 ==========
    const _Float16* W = wt + WT2_OFF;
    const _Float16* bp = W + (size_t)col*K2 + tg*8;
    float4v acc[5];
    #pragma unroll
    for (int kk = 0; kk < 5; ++kk) acc[kk] = z4;

    // --- (0,2,2): k=v*64+u, 16 double-steps ---
    #pragma unroll 2
    for (int so = 0; so < 16; ++so){
      half8v bf[2];
      #pragma unroll
      for (int sel = 0; sel < 2; ++sel) bf[sel] = ldH(bp + (2*so + sel)*32);
      half2v xq[5];
      #pragma unroll
      for (int k5 = 0; k5 < 5; ++k5) xq[k5] = bc2(rh + 160 + so*5 + k5);
      #pragma unroll
      for (int sel = 0; sel < 2; ++sel)
        #pragma unroll
        for (int k5 = 0; k5 < 5; ++k5){
          Frag af;
          #pragma unroll
          for (int tp = 0; tp < 4; ++tp) af.h2[tp] = pmul(xq[k5], x0w[sel].h2[tp]);
          acc[k5] = MF(af.h8, bf[sel], acc[k5]);
        }
    }
    // pair-transposed x1 window over v = tg*8..+8
    half2v xP[3][4];
    #pragma unroll
    for (int j = 0; j < 3; ++j)
      #pragma unroll
      for (int tp = 0; tp < 4; ++tp){
        _Float16 e0 = rh[64 + (tg*8 + 2*tp    )*3 + j];
        _Float16 e1 = rh[64 + (tg*8 + 2*tp + 1)*3 + j];
        half2v p = { e0, e1 }; xP[j][tp] = p;
      }
    // --- (1,1,2): k=u*32+v, 32 steps; y[j][kk] = sum_i C[i,j,kk]*x1[u][i] ---
    #pragma unroll 2
    for (int u = 0; u < 32; ++u){
      const half8v bf = ldH(bp + (32 + u)*32);
      float xi[3];
      #pragma unroll
      for (int i = 0; i < 3; ++i) xi[i] = (float)rh[64 + u*3 + i];
      half2v y2[3][5];
      #pragma unroll
      for (int j = 0; j < 3; ++j)
        #pragma unroll
        for (int kk = 0; kk < 5; ++kk){
          float y = 0.f;
          #pragma unroll
          for (int i = 0; i < 3; ++i){
            const double cd = T112.v[i][j][kk];
            if (NZ(cd)) y = fmaf((float)cd, xi[i], y);
          }
          y2[j][kk] = pk2(y, y);
        }
      #pragma unroll
      for (int kk = 0; kk < 5; ++kk){
        Frag af;
        #pragma unroll
        for (int tp = 0; tp < 4; ++tp)
          af.h2[tp] = pfma(xP[2][tp], y2[2][kk], pfma(xP[1][tp], y2[1][kk], pmul(xP[0][tp], y2[0][kk])));
        acc[kk] = MF(af.h8, bf, acc[kk]);
      }
    }
    // --- (2,0,2): k=u*64+v, 16 double-steps ---
    #pragma unroll 2
    for (int so = 0; so < 16; ++so){
      half8v bf[2];
      #pragma unroll
      for (int sel = 0; sel < 2; ++sel) bf[sel] = ldH(bp + (64 + 2*so + sel)*32);
      half2v xq[5];
      #pragma unroll
      for (int k5 = 0; k5 < 5; ++k5) xq[k5] = bc2(rh + 160 + so*5 + k5);
      #pragma unroll
      for (int sel = 0; sel < 2; ++sel)
        #pragma unroll
        for (int k5 = 0; k5 < 5; ++k5){
          Frag af;
          #pragma unroll
          for (int tp = 0; tp < 4; ++tp) af.h2[tp] = pmul(xq[k5], x0w[sel].h2[tp]);
          acc[k5] = MF(af.h8, bf[sel], acc[k5]);
        }
    }
    // --- (2,2,2): k=u*16+v, 8 steps; w[j][kk] = sum_i C[i,j,kk]*x2[u][i] ---
    half2v xQ[5][4];
    #pragma unroll
    for (int j = 0; j < 5; ++j)
      #pragma unroll
      for (int tp = 0; tp < 4; ++tp){
        _Float16 e0 = rh[160 + ((tg&1)*8 + 2*tp    )*5 + j];
        _Float16 e1 = rh[160 + ((tg&1)*8 + 2*tp + 1)*5 + j];
        half2v p = { e0, e1 }; xQ[j][tp] = p;
      }
    #pragma unroll 2
    for (int s8 = 0; s8 < 8; ++s8){
      const half8v bf = ldH(bp + (96 + s8)*32);
      const int u = 2*s8 + (tg >> 1);
      float xi[5];
      #pragma unroll
      for (int i = 0; i < 5; ++i) xi[i] = (float)rh[160 + u*5 + i];
      half2v w2[5][5];
      #pragma unroll
      for (int j = 0; j < 5; ++j)
        #pragma unroll
        for (int kk = 0; kk < 5; ++kk){
          float w = 0.f;
          #pragma unroll
          for (int i = 0; i < 5; ++i){
            const double cd = T222.v[i][j][kk];
            if (NZ(cd)) w = fmaf((float)cd, xi[i], w);
          }
          w2[j][kk] = pk2(w, w);
        }
      #pragma unroll
      for (int kk = 0; kk < 5; ++kk){
        Frag af;
        #pragma unroll
        for (int tp = 0; tp < 4; ++tp){
          half2v a = pmul(xQ[0][tp], w2[0][kk]);
          #pragma unroll
          for (int j = 1; j < 5; ++j) a = pfma(xQ[j][tp], w2[j][kk], a);
          af.h2[tp] = a;
        }
        acc[kk] = MF(af.h8, bf, acc[kk]);
      }
    }
    // --- store (5 consecutive floats per (b,w)) ---
    #pragma unroll
    for (int r = 0; r < 4; ++r){
      const int b = b0 + wv*16 + tg*4 + r;
      if (b < 20000){
        float* o = out + (size_t)b*240 + 160 + 5*col;
        o[0] = acc[0][r]; o[1] = acc[1][r]; o[2] = acc[2][r];
        o[3] = acc[3][r]; o[4] = acc[4][r];
      }
    }
  }
}

// ---------------------------------------------------------------------------
extern "C" void kernel_launch(void* const* d_in, const int* in_sizes, int n_in,
                              void* d_out, int out_size, void* d_ws, size_t ws_size,
                              hipStream_t stream){
  (void)in_sizes; (void)n_in; (void)out_size; (void)ws_size;
  const float* x = (const float*)d_in[0];
  const float* w[11];
  for (int i = 0; i < 11; ++i) w[i] = (const float*)d_in[1 + i];
  _Float16* wt = (_Float16*)d_ws;
  float* out = (float*)d_out;

  tsq_prep<<<(WT_TOT + 255)/256, 256, 0, stream>>>(w[0], w[1], w[2], w[3], w[4], w[5],
                                                   w[6], w[7], w[8], w[9], w[10], wt);
  dim3 gm(3, 313);
  tsq_main<<<gm, 256, 0, stream>>>(x, wt, out);
}